// Round 1
// baseline (3191.884 us; speedup 1.0000x reference)
//
#include <hip/hip_runtime.h>
#include <math.h>

#define DM    1024       // d_model
#define DI    2048       // d_inner
#define NST   16         // d_state
#define DTR   64         // dt_rank
#define TL    512        // T
#define NB    8          // batch
#define BT    4096       // NB*TL rows
#define XDBL  96         // dt_rank + 2*N

// ---------------- LayerNorm (one block per row of 1024) ----------------
__global__ __launch_bounds__(256) void ln_kernel(const float* __restrict__ x,
    const float* __restrict__ w, const float* __restrict__ b, float* __restrict__ out)
{
    const int row = blockIdx.x;
    const int tid = threadIdx.x;
    const float4 xv = *(const float4*)(x + (size_t)row * DM + tid * 4);
    float s  = xv.x + xv.y + xv.z + xv.w;
    float ss = xv.x*xv.x + xv.y*xv.y + xv.z*xv.z + xv.w*xv.w;
#pragma unroll
    for (int off = 32; off; off >>= 1) {
        s  += __shfl_down(s, off);
        ss += __shfl_down(ss, off);
    }
    __shared__ float red[10];
    const int wid = tid >> 6, lane = tid & 63;
    if (lane == 0) { red[wid] = s; red[4 + wid] = ss; }
    __syncthreads();
    if (tid == 0) {
        float S  = red[0] + red[1] + red[2] + red[3];
        float SS = red[4] + red[5] + red[6] + red[7];
        float mu  = S * (1.0f / DM);
        float var = SS * (1.0f / DM) - mu * mu;
        red[8] = mu;
        red[9] = rsqrtf(var + 1e-5f);
    }
    __syncthreads();
    const float mu = red[8], rs = red[9];
    const float4 wv = *(const float4*)(w + tid * 4);
    const float4 bv = *(const float4*)(b + tid * 4);
    float4 o;
    o.x = (xv.x - mu) * rs * wv.x + bv.x;
    o.y = (xv.y - mu) * rs * wv.y + bv.y;
    o.z = (xv.z - mu) * rs * wv.z + bv.z;
    o.w = (xv.w - mu) * rs * wv.w + bv.w;
    *(float4*)(out + (size_t)row * DM + tid * 4) = o;
}

// ---------------- Generic f32 NT GEMM: C[m,n] = sum_k A[m,k]*B[n,k] ----------
// EPI 0: none; 1: softplus(acc + aux[n]); 2: acc + aux[m*ldc+n] (residual)
template<int EPI>
__global__ __launch_bounds__(256) void gemm_nt(const float* __restrict__ A,
    const float* __restrict__ B, float* __restrict__ C, const float* __restrict__ aux,
    int M, int N, int K, int lda, int ldb, int ldc)
{
    __shared__ float As[16][132];
    __shared__ float Bs[16][132];
    const int tid = threadIdx.x;
    const int bm = blockIdx.y * 128, bn = blockIdx.x * 128;
    const int r0  = tid & 127;
    const int kq0 = (tid >> 7) * 4;          // 0 or 4
    const int m0  = (tid >> 4) * 8, n0 = (tid & 15) * 8;
    float acc[8][8] = {};
    const float* Ap = A + (size_t)(bm + r0) * lda + kq0;
    const float* Bp = B + (size_t)(bn + r0) * ldb + kq0;
    const bool bval = (bn + r0) < N;

    for (int k0 = 0; k0 < K; k0 += 16) {
        const float4 a0 = *(const float4*)(Ap + k0);
        const float4 a1 = *(const float4*)(Ap + k0 + 8);
        float4 b0 = make_float4(0.f, 0.f, 0.f, 0.f), b1 = b0;
        if (bval) {
            b0 = *(const float4*)(Bp + k0);
            b1 = *(const float4*)(Bp + k0 + 8);
        }
        As[kq0 + 0][r0] = a0.x; As[kq0 + 1][r0] = a0.y;
        As[kq0 + 2][r0] = a0.z; As[kq0 + 3][r0] = a0.w;
        As[kq0 + 8][r0] = a1.x; As[kq0 + 9][r0] = a1.y;
        As[kq0 +10][r0] = a1.z; As[kq0 +11][r0] = a1.w;
        Bs[kq0 + 0][r0] = b0.x; Bs[kq0 + 1][r0] = b0.y;
        Bs[kq0 + 2][r0] = b0.z; Bs[kq0 + 3][r0] = b0.w;
        Bs[kq0 + 8][r0] = b1.x; Bs[kq0 + 9][r0] = b1.y;
        Bs[kq0 +10][r0] = b1.z; Bs[kq0 +11][r0] = b1.w;
        __syncthreads();
#pragma unroll
        for (int kk = 0; kk < 16; ++kk) {
            float av[8], bv[8];
            *(float4*)&av[0] = *(const float4*)&As[kk][m0];
            *(float4*)&av[4] = *(const float4*)&As[kk][m0 + 4];
            *(float4*)&bv[0] = *(const float4*)&Bs[kk][n0];
            *(float4*)&bv[4] = *(const float4*)&Bs[kk][n0 + 4];
#pragma unroll
            for (int i = 0; i < 8; ++i)
#pragma unroll
                for (int j = 0; j < 8; ++j)
                    acc[i][j] += av[i] * bv[j];
        }
        __syncthreads();
    }

#pragma unroll
    for (int i = 0; i < 8; ++i) {
        const int m = bm + m0 + i;
        float* Crow = C + (size_t)m * ldc;
#pragma unroll
        for (int j = 0; j < 8; ++j) {
            const int n = bn + n0 + j;
            if (n < N) {
                float v = acc[i][j];
                if (EPI == 1) {
                    v += aux[n];
                    v = (v > 20.f) ? v : log1pf(expf(v));
                }
                if (EPI == 2) {
                    v += aux[(size_t)m * ldc + n];
                }
                Crow[n] = v;
            }
        }
    }
}

// ---------------- causal depthwise conv(4) + bias + SiLU ----------------
// reads xi columns (0..2047) of xz (row stride 4096), writes u (row stride 2048)
__global__ __launch_bounds__(256) void conv_silu_kernel(const float* __restrict__ xz,
    const float* __restrict__ cw, const float* __restrict__ cb, float* __restrict__ u)
{
    const int idx = blockIdx.x * 256 + threadIdx.x;   // over BT * 512 (d/4)
    const int d4 = idx & 511;
    const int bt = idx >> 9;
    const int t  = bt & (TL - 1);
    const int d  = d4 * 4;
    const float4 w0 = *(const float4*)(cw + (size_t)(d + 0) * 4);
    const float4 w1 = *(const float4*)(cw + (size_t)(d + 1) * 4);
    const float4 w2 = *(const float4*)(cw + (size_t)(d + 2) * 4);
    const float4 w3 = *(const float4*)(cw + (size_t)(d + 3) * 4);
    const float4 cbv = *(const float4*)(cb + d);
    float a0 = cbv.x, a1 = cbv.y, a2 = cbv.z, a3 = cbv.w;
    const float* base = xz + (size_t)bt * 4096 + d;
    if (t >= 3) {   // tap j=0 -> x[t-3]
        const float4 xv = *(const float4*)(base - 3 * 4096);
        a0 += xv.x * w0.x; a1 += xv.y * w1.x; a2 += xv.z * w2.x; a3 += xv.w * w3.x;
    }
    if (t >= 2) {   // tap j=1 -> x[t-2]
        const float4 xv = *(const float4*)(base - 2 * 4096);
        a0 += xv.x * w0.y; a1 += xv.y * w1.y; a2 += xv.z * w2.y; a3 += xv.w * w3.y;
    }
    if (t >= 1) {   // tap j=2 -> x[t-1]
        const float4 xv = *(const float4*)(base - 1 * 4096);
        a0 += xv.x * w0.z; a1 += xv.y * w1.z; a2 += xv.z * w2.z; a3 += xv.w * w3.z;
    }
    {               // tap j=3 -> x[t]
        const float4 xv = *(const float4*)(base);
        a0 += xv.x * w0.w; a1 += xv.y * w1.w; a2 += xv.z * w2.w; a3 += xv.w * w3.w;
    }
    float4 o;
    o.x = a0 / (1.f + expf(-a0));
    o.y = a1 / (1.f + expf(-a1));
    o.z = a2 / (1.f + expf(-a2));
    o.w = a3 / (1.f + expf(-a3));
    *(float4*)(u + (size_t)bt * DI + d) = o;
}

// ---------------- selective scan ----------------
// thread = (n, d_local); block = 16 d's x 16 n; grid = (DI/16, NB)
// writes gated output into xi columns (0..2047) of xz; reads res from cols 2048..
__global__ __launch_bounds__(256) void scan_kernel(
    const float* __restrict__ u, const float* __restrict__ dt,
    const float* __restrict__ xdbl, const float* __restrict__ A_log,
    const float* __restrict__ D_skip, float* __restrict__ xz)
{
    const int tid = threadIdx.x;
    const int n  = tid & 15;
    const int dl = tid >> 4;
    const int d  = blockIdx.x * 16 + dl;
    const int b  = blockIdx.y;
    const float a_l2 = -expf(A_log[(size_t)d * NST + n]) * 1.44269504088896340f;
    const float Dv = D_skip[d];
    float h = 0.f;
    const float* dtp  = dt   + (size_t)b * TL * DI + d;
    const float* up   = u    + (size_t)b * TL * DI + d;
    const float* xbp  = xdbl + (size_t)b * TL * XDBL;
    const float* resp = xz   + (size_t)b * TL * 4096 + 2048 + d;
    float*       yp   = xz   + (size_t)b * TL * 4096 + d;
    for (int t = 0; t < TL; ++t) {
        const float dtv = dtp[(size_t)t * DI];
        const float uv  = up[(size_t)t * DI];
        const float bv  = xbp[(size_t)t * XDBL + DTR + n];
        const float cv  = xbp[(size_t)t * XDBL + DTR + NST + n];
        const float da  = exp2f(dtv * a_l2);
        h = h * da + (dtv * uv) * bv;
        float y = h * cv;
        y += __shfl_xor(y, 1);
        y += __shfl_xor(y, 2);
        y += __shfl_xor(y, 4);
        y += __shfl_xor(y, 8);
        if (n == 0) {
            const float res = resp[(size_t)t * 4096];
            const float sig = 1.f / (1.f + expf(-res));
            yp[(size_t)t * 4096] = (y + uv * Dv) * (res * sig);
        }
    }
}

extern "C" void kernel_launch(void* const* d_in, const int* in_sizes, int n_in,
                              void* d_out, int out_size, void* d_ws, size_t ws_size,
                              hipStream_t stream)
{
    const float* x      = (const float*)d_in[0];
    const float* ln_w   = (const float*)d_in[1];
    const float* ln_b   = (const float*)d_in[2];
    const float* in_w   = (const float*)d_in[3];
    const float* cw     = (const float*)d_in[4];
    const float* cb     = (const float*)d_in[5];
    const float* xp_w   = (const float*)d_in[6];
    const float* dtp_w  = (const float*)d_in[7];
    const float* dtp_b  = (const float*)d_in[8];
    const float* A_log  = (const float*)d_in[9];
    const float* D_skip = (const float*)d_in[10];
    const float* out_w  = (const float*)d_in[11];
    float* out = (float*)d_out;

    float* xz   = (float*)d_ws;                  // BT x 4096
    float* u    = xz   + (size_t)BT * 4096;      // BT x 2048
    float* dtb  = u    + (size_t)BT * DI;        // BT x 2048
    float* xdbl = dtb  + (size_t)BT * DI;        // BT x 96
    float* xn   = xdbl + (size_t)BT * XDBL;      // BT x 1024

    for (int L = 0; L < 2; ++L) {
        const float* xin = (L == 0) ? x : out;
        ln_kernel<<<BT, 256, 0, stream>>>(xin, ln_w + L * DM, ln_b + L * DM, xn);
        // in_proj: (BT,1024) x (4096,1024)^T -> xz (BT,4096)
        gemm_nt<0><<<dim3(4096 / 128, BT / 128), 256, 0, stream>>>(
            xn, in_w + (size_t)L * 4096 * DM, xz, nullptr,
            BT, 4096, DM, DM, DM, 4096);
        // conv + silu -> u
        conv_silu_kernel<<<(BT * (DI / 4)) / 256, 256, 0, stream>>>(
            xz, cw + (size_t)L * DI * 4, cb + (size_t)L * DI, u);
        // x_proj: (BT,2048) x (96,2048)^T -> xdbl (BT,96)
        gemm_nt<0><<<dim3(1, BT / 128), 256, 0, stream>>>(
            u, xp_w + (size_t)L * XDBL * DI, xdbl, nullptr,
            BT, XDBL, DI, DI, DI, XDBL);
        // dt_proj + softplus: (BT,64) x (2048,64)^T -> dtb (BT,2048)
        gemm_nt<1><<<dim3(DI / 128, BT / 128), 256, 0, stream>>>(
            xdbl, dtp_w + (size_t)L * DI * DTR, dtb, dtp_b + (size_t)L * DI,
            BT, DI, DTR, XDBL, DTR, DI);
        // selective scan (+ D skip + silu(res) gate) -> xi cols of xz
        scan_kernel<<<dim3(DI / 16, NB), 256, 0, stream>>>(
            u, dtb, xdbl, A_log + (size_t)L * DI * NST, D_skip + (size_t)L * DI, xz);
        // out_proj + residual: (BT,2048) x (1024,2048)^T + xin -> out
        gemm_nt<2><<<dim3(DM / 128, BT / 128), 256, 0, stream>>>(
            xz, out_w + (size_t)L * DM * DI, out, xin,
            BT, DM, DI, 4096, DI, DM);
    }
}

// Round 2
// 1214.220 us; speedup vs baseline: 2.6288x; 2.6288x over previous
//
#include <hip/hip_runtime.h>
#include <math.h>

#define DM    1024       // d_model
#define DI    2048       // d_inner
#define NST   16         // d_state
#define DTR   64         // dt_rank
#define TL    512        // T
#define NB    8          // batch
#define BT    4096       // NB*TL rows
#define XDBL  96         // dt_rank + 2*N

typedef __attribute__((ext_vector_type(8))) short short8;
typedef __attribute__((ext_vector_type(4))) float f32x4;

__device__ inline ushort f2bf(float x) {
    union { float f; unsigned u; } c; c.f = x;
    unsigned r = c.u + 0x7fffu + ((c.u >> 16) & 1u);
    return (ushort)(r >> 16);
}
__device__ inline float bf2f(ushort u) {
    union { unsigned u; float f; } c; c.u = ((unsigned)u) << 16; return c.f;
}
__device__ inline void gload16(const void* g, void* l) {
    __builtin_amdgcn_global_load_lds(
        (const __attribute__((address_space(1))) unsigned int*)g,
        (__attribute__((address_space(3))) unsigned int*)l, 16, 0, 0);
}

// ---------------- f32 -> bf16 converters ----------------
__global__ __launch_bounds__(256) void cvt4(const float* __restrict__ in,
                                            ushort* __restrict__ out)
{
    const int i = blockIdx.x * 256 + threadIdx.x;
    const float4 v = ((const float4*)in)[i];
    ushort4 o;
    o.x = f2bf(v.x); o.y = f2bf(v.y); o.z = f2bf(v.z); o.w = f2bf(v.w);
    ((ushort4*)out)[i] = o;
}

// xp_w: [2][96][2048] f32 -> [2][128][2048] bf16 zero-padded
__global__ __launch_bounds__(256) void cvt_xpw_k(const float* __restrict__ in,
                                                 ushort* __restrict__ out)
{
    const int i = blockIdx.x * 256 + threadIdx.x;     // 2*128*512
    const int c4 = i & 511, row = (i >> 9) & 127, lyr = i >> 16;
    ushort4 o;
    if (row < XDBL) {
        const float4 v = *(const float4*)(in + ((size_t)lyr * XDBL + row) * DI + c4 * 4);
        o.x = f2bf(v.x); o.y = f2bf(v.y); o.z = f2bf(v.z); o.w = f2bf(v.w);
    } else { o.x = 0; o.y = 0; o.z = 0; o.w = 0; }
    *(ushort4*)(out + ((size_t)lyr * 128 + row) * DI + c4 * 4) = o;
}

// ---------------- LayerNorm -> bf16 ----------------
__global__ __launch_bounds__(256) void ln_kernel(const float* __restrict__ x,
    const float* __restrict__ w, const float* __restrict__ b, ushort* __restrict__ out)
{
    const int row = blockIdx.x;
    const int tid = threadIdx.x;
    const float4 xv = *(const float4*)(x + (size_t)row * DM + tid * 4);
    float s  = xv.x + xv.y + xv.z + xv.w;
    float ss = xv.x*xv.x + xv.y*xv.y + xv.z*xv.z + xv.w*xv.w;
#pragma unroll
    for (int off = 32; off; off >>= 1) {
        s  += __shfl_down(s, off);
        ss += __shfl_down(ss, off);
    }
    __shared__ float red[10];
    const int wid = tid >> 6, lane = tid & 63;
    if (lane == 0) { red[wid] = s; red[4 + wid] = ss; }
    __syncthreads();
    if (tid == 0) {
        float S  = red[0] + red[1] + red[2] + red[3];
        float SS = red[4] + red[5] + red[6] + red[7];
        float mu  = S * (1.0f / DM);
        float var = SS * (1.0f / DM) - mu * mu;
        red[8] = mu;
        red[9] = rsqrtf(var + 1e-5f);
    }
    __syncthreads();
    const float mu = red[8], rs = red[9];
    const float4 wv = *(const float4*)(w + tid * 4);
    const float4 bv = *(const float4*)(b + tid * 4);
    ushort4 o;
    o.x = f2bf((xv.x - mu) * rs * wv.x + bv.x);
    o.y = f2bf((xv.y - mu) * rs * wv.y + bv.y);
    o.z = f2bf((xv.z - mu) * rs * wv.z + bv.z);
    o.w = f2bf((xv.w - mu) * rs * wv.w + bv.w);
    *(ushort4*)(out + (size_t)row * DM + tid * 4) = o;
}

// ---------------- bf16 MFMA NT GEMM: C[m,n] = sum_k A[m,k]*B[n,k] ----------
// 128x128 tile, BK=64, 4 waves each 64x64 (4x4 frags of 16x16x32).
// EPI 0: C=f32           (in_proj)
// EPI 1: C=f32 + C16=bf16, store only n<N   (x_proj)
// EPI 2: C=f32 softplus(acc+aux[n])          (dt_proj)
// EPI 3: C=f32 acc+aux[m*ldc+n] (residual)   (out_proj)
template<int EPI>
__global__ __launch_bounds__(256) void gemm_bf16(const ushort* __restrict__ A,
    const ushort* __restrict__ B, float* __restrict__ C, ushort* __restrict__ C16,
    const float* __restrict__ aux, int K, int lda, int ldb, int ldc, int N)
{
    __shared__ __align__(16) ushort Alds[128 * 64];
    __shared__ __align__(16) ushort Blds[128 * 64];
    const int tid = threadIdx.x;
    const int bm = blockIdx.y * 128, bn = blockIdx.x * 128;
    const int l = tid & 63, w = tid >> 6;
    const int wr = w >> 1, wc = w & 1;

    // staging: round r covers rows r*32 + tid/8, col-bytes (tid&7)*16
    const int srow = tid >> 3;          // 0..31
    const int scol = (tid & 7) * 8;     // element col
    const char* ap = (const char*)(A + (size_t)(bm + srow) * lda + scol);
    const char* bp = (const char*)(B + (size_t)(bn + srow) * ldb + scol);
    const size_t astep = (size_t)lda * 2 * 32;   // 32 rows
    const size_t bstep = (size_t)ldb * 2 * 32;

    f32x4 acc[4][4] = {};
    const int a_row = wr * 64 + (l & 15);
    const int b_row = wc * 64 + (l & 15);
    const int kcol  = (l >> 4) * 8;

    for (int k0 = 0; k0 < K; k0 += 64) {
#pragma unroll
        for (int r = 0; r < 4; ++r) {
            gload16(ap + r * astep + (size_t)k0 * 2, (char*)Alds + r * 4096 + tid * 16);
            gload16(bp + r * bstep + (size_t)k0 * 2, (char*)Blds + r * 4096 + tid * 16);
        }
        __syncthreads();
        short8 af[4][2], bfr[4][2];
#pragma unroll
        for (int i = 0; i < 4; ++i)
#pragma unroll
            for (int kh = 0; kh < 2; ++kh) {
                af[i][kh]  = *(const short8*)&Alds[(a_row + i * 16) * 64 + kh * 32 + kcol];
                bfr[i][kh] = *(const short8*)&Blds[(b_row + i * 16) * 64 + kh * 32 + kcol];
            }
#pragma unroll
        for (int i = 0; i < 4; ++i)
#pragma unroll
            for (int j = 0; j < 4; ++j) {
                acc[i][j] = __builtin_amdgcn_mfma_f32_16x16x32_bf16(af[i][0], bfr[j][0], acc[i][j], 0, 0, 0);
                acc[i][j] = __builtin_amdgcn_mfma_f32_16x16x32_bf16(af[i][1], bfr[j][1], acc[i][j], 0, 0, 0);
            }
        __syncthreads();
    }

    const int m0 = bm + wr * 64 + (l >> 4) * 4;
    const int n0 = bn + wc * 64 + (l & 15);
#pragma unroll
    for (int i = 0; i < 4; ++i)
#pragma unroll
        for (int j = 0; j < 4; ++j) {
            const int n = n0 + j * 16;
            if (EPI == 1 && n >= N) continue;
#pragma unroll
            for (int r = 0; r < 4; ++r) {
                const size_t m = (size_t)(m0 + i * 16 + r);
                float v = acc[i][j][r];
                if (EPI == 2) { v += aux[n]; v = (v > 20.f) ? v : log1pf(expf(v)); }
                if (EPI == 3) { v += aux[m * ldc + n]; }
                C[m * ldc + n] = v;
                if (EPI == 1) C16[m * ldc + n] = f2bf(v);
            }
        }
}

// ---------------- causal depthwise conv(4)+bias+SiLU -> u16; silu(res) -> g16 ----
__global__ __launch_bounds__(256) void conv_silu_kernel(const float* __restrict__ xz,
    const float* __restrict__ cw, const float* __restrict__ cb,
    ushort* __restrict__ u16, ushort* __restrict__ g16)
{
    const int idx = blockIdx.x * 256 + threadIdx.x;   // BT * 512
    const int d4 = idx & 511;
    const int bt = idx >> 9;
    const int t  = bt & (TL - 1);
    const int d  = d4 * 4;
    const float4 w0 = *(const float4*)(cw + (size_t)(d + 0) * 4);
    const float4 w1 = *(const float4*)(cw + (size_t)(d + 1) * 4);
    const float4 w2 = *(const float4*)(cw + (size_t)(d + 2) * 4);
    const float4 w3 = *(const float4*)(cw + (size_t)(d + 3) * 4);
    const float4 cbv = *(const float4*)(cb + d);
    float a0 = cbv.x, a1 = cbv.y, a2 = cbv.z, a3 = cbv.w;
    const float* base = xz + (size_t)bt * 4096 + d;
    if (t >= 3) {
        const float4 xv = *(const float4*)(base - 3 * 4096);
        a0 += xv.x * w0.x; a1 += xv.y * w1.x; a2 += xv.z * w2.x; a3 += xv.w * w3.x;
    }
    if (t >= 2) {
        const float4 xv = *(const float4*)(base - 2 * 4096);
        a0 += xv.x * w0.y; a1 += xv.y * w1.y; a2 += xv.z * w2.y; a3 += xv.w * w3.y;
    }
    if (t >= 1) {
        const float4 xv = *(const float4*)(base - 1 * 4096);
        a0 += xv.x * w0.z; a1 += xv.y * w1.z; a2 += xv.z * w2.z; a3 += xv.w * w3.z;
    }
    {
        const float4 xv = *(const float4*)(base);
        a0 += xv.x * w0.w; a1 += xv.y * w1.w; a2 += xv.z * w2.w; a3 += xv.w * w3.w;
    }
    ushort4 o;
    o.x = f2bf(a0 / (1.f + expf(-a0)));
    o.y = f2bf(a1 / (1.f + expf(-a1)));
    o.z = f2bf(a2 / (1.f + expf(-a2)));
    o.w = f2bf(a3 / (1.f + expf(-a3)));
    *(ushort4*)(u16 + (size_t)bt * DI + d) = o;
    // gate = silu(res), res = xz cols 2048..4095
    const float4 rv = *(const float4*)(base + 2048);
    ushort4 g;
    g.x = f2bf(rv.x / (1.f + expf(-rv.x)));
    g.y = f2bf(rv.y / (1.f + expf(-rv.y)));
    g.z = f2bf(rv.z / (1.f + expf(-rv.z)));
    g.w = f2bf(rv.w / (1.f + expf(-rv.w)));
    *(ushort4*)(g16 + (size_t)bt * DI + d) = g;
}

// ---------------- selective scan -> y16 (gated, bf16) ----------------
__global__ __launch_bounds__(256) void scan_kernel(
    const ushort* __restrict__ u16, const float* __restrict__ dt,
    const float* __restrict__ xdbl, const float* __restrict__ A_log,
    const float* __restrict__ D_skip, const ushort* __restrict__ g16,
    ushort* __restrict__ y16)
{
    const int tid = threadIdx.x;
    const int n  = tid & 15;
    const int dl = tid >> 4;
    const int d  = blockIdx.x * 16 + dl;
    const int b  = blockIdx.y;
    const float a_l2 = -expf(A_log[(size_t)d * NST + n]) * 1.44269504088896340f;
    const float Dv = D_skip[d];
    float h = 0.f;
    const float*  dtp = dt   + (size_t)b * TL * DI + d;
    const ushort* up  = u16  + (size_t)b * TL * DI + d;
    const float*  xbp = xdbl + (size_t)b * TL * XDBL;
    const ushort* gp  = g16  + (size_t)b * TL * DI + d;
    ushort*       yp  = y16  + (size_t)b * TL * DI + d;
    for (int t = 0; t < TL; ++t) {
        const float dtv = dtp[(size_t)t * DI];
        const float uv  = bf2f(up[(size_t)t * DI]);
        const float bv  = xbp[(size_t)t * XDBL + DTR + n];
        const float cv  = xbp[(size_t)t * XDBL + DTR + NST + n];
        const float da  = exp2f(dtv * a_l2);
        h = h * da + (dtv * uv) * bv;
        float y = h * cv;
        y += __shfl_xor(y, 1);
        y += __shfl_xor(y, 2);
        y += __shfl_xor(y, 4);
        y += __shfl_xor(y, 8);
        if (n == 0) {
            const float g = bf2f(gp[(size_t)t * DI]);
            yp[(size_t)t * DI] = f2bf((y + uv * Dv) * g);
        }
    }
}

extern "C" void kernel_launch(void* const* d_in, const int* in_sizes, int n_in,
                              void* d_out, int out_size, void* d_ws, size_t ws_size,
                              hipStream_t stream)
{
    const float* x      = (const float*)d_in[0];
    const float* ln_w   = (const float*)d_in[1];
    const float* ln_b   = (const float*)d_in[2];
    const float* in_w   = (const float*)d_in[3];
    const float* cw     = (const float*)d_in[4];
    const float* cb     = (const float*)d_in[5];
    const float* xp_w   = (const float*)d_in[6];
    const float* dtp_w  = (const float*)d_in[7];
    const float* dtp_b  = (const float*)d_in[8];
    const float* A_log  = (const float*)d_in[9];
    const float* D_skip = (const float*)d_in[10];
    const float* out_w  = (const float*)d_in[11];
    float* out = (float*)d_out;

    char* p = (char*)d_ws;
    float*  xz     = (float*)p;  p += (size_t)BT * 4096 * 4;   // 64MB
    float*  dtb    = (float*)p;  p += (size_t)BT * DI * 4;     // 32MB
    float*  xdbl   = (float*)p;  p += (size_t)BT * XDBL * 4;   // 1.5MB
    ushort* xn16   = (ushort*)p; p += (size_t)BT * DM * 2;     // 8MB
    ushort* u16    = (ushort*)p; p += (size_t)BT * DI * 2;     // 16MB
    ushort* g16    = (ushort*)p; p += (size_t)BT * DI * 2;     // 16MB
    ushort* y16    = (ushort*)p; p += (size_t)BT * DI * 2;     // 16MB
    ushort* xdbl16 = (ushort*)p; p += (size_t)BT * XDBL * 2;   // 0.75MB
    ushort* inw16  = (ushort*)p; p += (size_t)2 * 4096 * DM * 2;   // 16.8MB
    ushort* xpw16  = (ushort*)p; p += (size_t)2 * 128 * DI * 2;    // 1MB
    ushort* dtpw16 = (ushort*)p; p += (size_t)2 * DI * DTR * 2;    // 0.5MB
    ushort* outw16 = (ushort*)p; p += (size_t)2 * DM * DI * 2;     // 8.4MB

    // weight conversions (both layers)
    cvt4<<<(2 * 4096 * DM / 4) / 256, 256, 0, stream>>>(in_w, inw16);
    cvt_xpw_k<<<(2 * 128 * DI / 4) / 256, 256, 0, stream>>>(xp_w, xpw16);
    cvt4<<<(2 * DI * DTR / 4) / 256, 256, 0, stream>>>(dtp_w, dtpw16);
    cvt4<<<(2 * DM * DI / 4) / 256, 256, 0, stream>>>(out_w, outw16);

    for (int L = 0; L < 2; ++L) {
        const float* xin = (L == 0) ? x : out;
        ln_kernel<<<BT, 256, 0, stream>>>(xin, ln_w + L * DM, ln_b + L * DM, xn16);
        // in_proj: (BT,1024)x(4096,1024)^T -> xz f32
        gemm_bf16<0><<<dim3(4096 / 128, BT / 128), 256, 0, stream>>>(
            xn16, inw16 + (size_t)L * 4096 * DM, xz, nullptr, nullptr,
            DM, DM, DM, 4096, 4096);
        conv_silu_kernel<<<(BT * (DI / 4)) / 256, 256, 0, stream>>>(
            xz, cw + (size_t)L * DI * 4, cb + (size_t)L * DI, u16, g16);
        // x_proj: (BT,2048)x(96,2048)^T -> xdbl f32 + xdbl16
        gemm_bf16<1><<<dim3(1, BT / 128), 256, 0, stream>>>(
            u16, xpw16 + (size_t)L * 128 * DI, xdbl, xdbl16, nullptr,
            DI, DI, DI, XDBL, XDBL);
        // dt_proj + softplus: (BT,64)x(2048,64)^T -> dtb f32
        gemm_bf16<2><<<dim3(DI / 128, BT / 128), 256, 0, stream>>>(
            xdbl16, dtpw16 + (size_t)L * DI * DTR, dtb, nullptr, dtp_b + (size_t)L * DI,
            DTR, XDBL, DTR, DI, DI);
        // selective scan + D-skip + gate -> y16
        scan_kernel<<<dim3(DI / 16, NB), 256, 0, stream>>>(
            u16, dtb, xdbl, A_log + (size_t)L * DI * NST, D_skip + (size_t)L * DI,
            g16, y16);
        // out_proj + residual: (BT,2048)x(1024,2048)^T + xin -> out
        gemm_bf16<3><<<dim3(DM / 128, BT / 128), 256, 0, stream>>>(
            y16, outw16 + (size_t)L * DM * DI, out, nullptr, xin,
            DI, DI, DI, DM, DM);
    }
}

// Round 3
// 610.679 us; speedup vs baseline: 5.2268x; 1.9883x over previous
//
#include <hip/hip_runtime.h>
#include <math.h>

#define DM    1024       // d_model
#define DI    2048       // d_inner
#define NST   16         // d_state
#define DTR   64         // dt_rank
#define TL    512        // T
#define NB    8          // batch
#define BT    4096       // NB*TL rows
#define XDBL  96         // dt_rank + 2*N
#define NCH   16         // scan chunks
#define TC    32         // chunk length

typedef __attribute__((ext_vector_type(8))) short short8;
typedef __attribute__((ext_vector_type(4))) float f32x4;

__device__ inline ushort f2bf(float x) {
    union { float f; unsigned u; } c; c.f = x;
    unsigned r = c.u + 0x7fffu + ((c.u >> 16) & 1u);
    return (ushort)(r >> 16);
}
__device__ inline float bf2f(ushort u) {
    union { unsigned u; float f; } c; c.u = ((unsigned)u) << 16; return c.f;
}
__device__ inline void gload16(const void* g, void* l) {
    __builtin_amdgcn_global_load_lds(
        (const __attribute__((address_space(1))) unsigned int*)g,
        (__attribute__((address_space(3))) unsigned int*)l, 16, 0, 0);
}

// ---------------- f32 -> bf16 converters ----------------
__global__ __launch_bounds__(256) void cvt4(const float* __restrict__ in,
                                            ushort* __restrict__ out)
{
    const int i = blockIdx.x * 256 + threadIdx.x;
    const float4 v = ((const float4*)in)[i];
    ushort4 o;
    o.x = f2bf(v.x); o.y = f2bf(v.y); o.z = f2bf(v.z); o.w = f2bf(v.w);
    ((ushort4*)out)[i] = o;
}

// xp_w: [2][96][2048] f32 -> [2][128][2048] bf16 zero-padded
__global__ __launch_bounds__(256) void cvt_xpw_k(const float* __restrict__ in,
                                                 ushort* __restrict__ out)
{
    const int i = blockIdx.x * 256 + threadIdx.x;     // 2*128*512
    const int c4 = i & 511, row = (i >> 9) & 127, lyr = i >> 16;
    ushort4 o;
    if (row < XDBL) {
        const float4 v = *(const float4*)(in + ((size_t)lyr * XDBL + row) * DI + c4 * 4);
        o.x = f2bf(v.x); o.y = f2bf(v.y); o.z = f2bf(v.z); o.w = f2bf(v.w);
    } else { o.x = 0; o.y = 0; o.z = 0; o.w = 0; }
    *(ushort4*)(out + ((size_t)lyr * 128 + row) * DI + c4 * 4) = o;
}

// ---------------- LayerNorm -> bf16 ----------------
__global__ __launch_bounds__(256) void ln_kernel(const float* __restrict__ x,
    const float* __restrict__ w, const float* __restrict__ b, ushort* __restrict__ out)
{
    const int row = blockIdx.x;
    const int tid = threadIdx.x;
    const float4 xv = *(const float4*)(x + (size_t)row * DM + tid * 4);
    float s  = xv.x + xv.y + xv.z + xv.w;
    float ss = xv.x*xv.x + xv.y*xv.y + xv.z*xv.z + xv.w*xv.w;
#pragma unroll
    for (int off = 32; off; off >>= 1) {
        s  += __shfl_down(s, off);
        ss += __shfl_down(ss, off);
    }
    __shared__ float red[10];
    const int wid = tid >> 6, lane = tid & 63;
    if (lane == 0) { red[wid] = s; red[4 + wid] = ss; }
    __syncthreads();
    if (tid == 0) {
        float S  = red[0] + red[1] + red[2] + red[3];
        float SS = red[4] + red[5] + red[6] + red[7];
        float mu  = S * (1.0f / DM);
        float var = SS * (1.0f / DM) - mu * mu;
        red[8] = mu;
        red[9] = rsqrtf(var + 1e-5f);
    }
    __syncthreads();
    const float mu = red[8], rs = red[9];
    const float4 wv = *(const float4*)(w + tid * 4);
    const float4 bv = *(const float4*)(b + tid * 4);
    ushort4 o;
    o.x = f2bf((xv.x - mu) * rs * wv.x + bv.x);
    o.y = f2bf((xv.y - mu) * rs * wv.y + bv.y);
    o.z = f2bf((xv.z - mu) * rs * wv.z + bv.z);
    o.w = f2bf((xv.w - mu) * rs * wv.w + bv.w);
    *(ushort4*)(out + (size_t)row * DM + tid * 4) = o;
}

// ---------------- bf16 MFMA NT GEMM: C[m,n] = sum_k A[m,k]*B[n,k] ----------
// 128x128 tile, BK=64, 4 waves each 64x64 (4x4 frags of 16x16x32).
// Split-K via blockIdx.z: each z handles Ksub, stores at C + z*czstride.
// EPI 0: plain f32
// EPI 2: softplus(acc + aux[n])
// EPI 3: acc + aux[m*ldc+n] (residual)
// EPI 4: plain f32, guarded n<N (partial store, ldc<128)
template<int EPI>
__global__ __launch_bounds__(256) void gemm_bf16(const ushort* __restrict__ A,
    const ushort* __restrict__ B, float* __restrict__ C,
    const float* __restrict__ aux, int Ksub, int lda, int ldb, int ldc, int N,
    size_t czstride)
{
    __shared__ __align__(16) ushort Alds[128 * 64];
    __shared__ __align__(16) ushort Blds[128 * 64];
    const int tid = threadIdx.x;
    const int bm = blockIdx.y * 128, bn = blockIdx.x * 128;
    const int l = tid & 63, w = tid >> 6;
    const int wr = w >> 1, wc = w & 1;

    const int srow = tid >> 3;          // 0..31
    const int scol = (tid & 7) * 8;     // element col
    const char* ap = (const char*)(A + (size_t)(bm + srow) * lda + scol);
    const char* bp = (const char*)(B + (size_t)(bn + srow) * ldb + scol);
    const size_t astep = (size_t)lda * 2 * 32;   // 32 rows
    const size_t bstep = (size_t)ldb * 2 * 32;

    f32x4 acc[4][4] = {};
    const int a_row = wr * 64 + (l & 15);
    const int b_row = wc * 64 + (l & 15);
    const int kcol  = (l >> 4) * 8;
    const int kbeg  = blockIdx.z * Ksub;

    for (int k0 = kbeg; k0 < kbeg + Ksub; k0 += 64) {
#pragma unroll
        for (int r = 0; r < 4; ++r) {
            gload16(ap + r * astep + (size_t)k0 * 2, (char*)Alds + r * 4096 + tid * 16);
            gload16(bp + r * bstep + (size_t)k0 * 2, (char*)Blds + r * 4096 + tid * 16);
        }
        __syncthreads();
        short8 af[4][2], bfr[4][2];
#pragma unroll
        for (int i = 0; i < 4; ++i)
#pragma unroll
            for (int kh = 0; kh < 2; ++kh) {
                af[i][kh]  = *(const short8*)&Alds[(a_row + i * 16) * 64 + kh * 32 + kcol];
                bfr[i][kh] = *(const short8*)&Blds[(b_row + i * 16) * 64 + kh * 32 + kcol];
            }
#pragma unroll
        for (int i = 0; i < 4; ++i)
#pragma unroll
            for (int j = 0; j < 4; ++j) {
                acc[i][j] = __builtin_amdgcn_mfma_f32_16x16x32_bf16(af[i][0], bfr[j][0], acc[i][j], 0, 0, 0);
                acc[i][j] = __builtin_amdgcn_mfma_f32_16x16x32_bf16(af[i][1], bfr[j][1], acc[i][j], 0, 0, 0);
            }
        __syncthreads();
    }

    C += (size_t)blockIdx.z * czstride;
    const int m0 = bm + wr * 64 + (l >> 4) * 4;
    const int n0 = bn + wc * 64 + (l & 15);
#pragma unroll
    for (int i = 0; i < 4; ++i)
#pragma unroll
        for (int j = 0; j < 4; ++j) {
            const int n = n0 + j * 16;
            if (EPI == 4 && n >= N) continue;
#pragma unroll
            for (int r = 0; r < 4; ++r) {
                const size_t m = (size_t)(m0 + i * 16 + r);
                float v = acc[i][j][r];
                if (EPI == 2) { v += aux[n]; v = (v > 20.f) ? v : log1pf(expf(v)); }
                if (EPI == 3) { v += aux[m * ldc + n]; }
                C[m * ldc + n] = v;
            }
        }
}

// ---------------- x_proj split-K reduce: 4 partials -> xdbl f32 + bf16 -------
__global__ __launch_bounds__(256) void xdbl_reduce(const float* __restrict__ part,
    float* __restrict__ xdbl, ushort* __restrict__ xdbl16)
{
    const int i = blockIdx.x * 256 + threadIdx.x;   // BT*XDBL/4
    const size_t s4 = (size_t)BT * XDBL / 4;
    float4 a = ((const float4*)part)[i];
    const float4 b = ((const float4*)part)[i + s4];
    const float4 c = ((const float4*)part)[i + 2 * s4];
    const float4 d = ((const float4*)part)[i + 3 * s4];
    a.x += b.x + c.x + d.x;
    a.y += b.y + c.y + d.y;
    a.z += b.z + c.z + d.z;
    a.w += b.w + c.w + d.w;
    ((float4*)xdbl)[i] = a;
    ushort4 o;
    o.x = f2bf(a.x); o.y = f2bf(a.y); o.z = f2bf(a.z); o.w = f2bf(a.w);
    ((ushort4*)xdbl16)[i] = o;
}

// ---------------- causal depthwise conv(4)+bias+SiLU -> u16; silu(res) -> g16 ----
__global__ __launch_bounds__(256) void conv_silu_kernel(const float* __restrict__ xz,
    const float* __restrict__ cw, const float* __restrict__ cb,
    ushort* __restrict__ u16, ushort* __restrict__ g16)
{
    const int idx = blockIdx.x * 256 + threadIdx.x;   // BT * 512
    const int d4 = idx & 511;
    const int bt = idx >> 9;
    const int t  = bt & (TL - 1);
    const int d  = d4 * 4;
    const float4 w0 = *(const float4*)(cw + (size_t)(d + 0) * 4);
    const float4 w1 = *(const float4*)(cw + (size_t)(d + 1) * 4);
    const float4 w2 = *(const float4*)(cw + (size_t)(d + 2) * 4);
    const float4 w3 = *(const float4*)(cw + (size_t)(d + 3) * 4);
    const float4 cbv = *(const float4*)(cb + d);
    float a0 = cbv.x, a1 = cbv.y, a2 = cbv.z, a3 = cbv.w;
    const float* base = xz + (size_t)bt * 4096 + d;
    if (t >= 3) {
        const float4 xv = *(const float4*)(base - 3 * 4096);
        a0 += xv.x * w0.x; a1 += xv.y * w1.x; a2 += xv.z * w2.x; a3 += xv.w * w3.x;
    }
    if (t >= 2) {
        const float4 xv = *(const float4*)(base - 2 * 4096);
        a0 += xv.x * w0.y; a1 += xv.y * w1.y; a2 += xv.z * w2.y; a3 += xv.w * w3.y;
    }
    if (t >= 1) {
        const float4 xv = *(const float4*)(base - 1 * 4096);
        a0 += xv.x * w0.z; a1 += xv.y * w1.z; a2 += xv.z * w2.z; a3 += xv.w * w3.z;
    }
    {
        const float4 xv = *(const float4*)(base);
        a0 += xv.x * w0.w; a1 += xv.y * w1.w; a2 += xv.z * w2.w; a3 += xv.w * w3.w;
    }
    ushort4 o;
    o.x = f2bf(a0 / (1.f + expf(-a0)));
    o.y = f2bf(a1 / (1.f + expf(-a1)));
    o.z = f2bf(a2 / (1.f + expf(-a2)));
    o.w = f2bf(a3 / (1.f + expf(-a3)));
    *(ushort4*)(u16 + (size_t)bt * DI + d) = o;
    const float4 rv = *(const float4*)(base + 2048);
    ushort4 g;
    g.x = f2bf(rv.x / (1.f + expf(-rv.x)));
    g.y = f2bf(rv.y / (1.f + expf(-rv.y)));
    g.z = f2bf(rv.z / (1.f + expf(-rv.z)));
    g.w = f2bf(rv.w / (1.f + expf(-rv.w)));
    *(ushort4*)(g16 + (size_t)bt * DI + d) = g;
}

// ---------------- chunked selective scan ----------------
// Pass A: per (b,chunk,d) thread: local scan (h0=0) over TC steps, h[16] in regs.
//         Outputs hA (local final state) and sdt (sum of dt over chunk).
// Pass B: per (b,d,n): combine 16 chunk summaries sequentially -> Hs (init state/chunk).
// Pass C: re-run chunks from Hs, emit y = C.h + D*u, gated, bf16.
__global__ __launch_bounds__(256) void scan_partA(
    const float* __restrict__ dt, const ushort* __restrict__ u16,
    const float* __restrict__ xdbl, const float* __restrict__ A_log,
    float* __restrict__ hA, float* __restrict__ sdtA)
{
    __shared__ float bc[TC][32];
    const int tid = threadIdx.x;
    const int d  = blockIdx.x * 256 + tid;
    const int c  = blockIdx.y;
    const int b  = blockIdx.z;
    const int t0 = c * TC;
    {   // stage B/C: rows t0..t0+TC-1, cols 64..95 of xdbl[b]
        const int r = tid >> 3, cq = tid & 7;
        const float* src = xdbl + (size_t)(b * TL + t0 + r) * XDBL + 64 + cq * 4;
        *(float4*)&bc[r][cq * 4] = *(const float4*)src;
    }
    float aL2[16];
#pragma unroll
    for (int q = 0; q < 4; ++q) {
        const float4 av = *(const float4*)(A_log + (size_t)d * NST + q * 4);
        aL2[q*4+0] = -expf(av.x) * 1.44269504f;
        aL2[q*4+1] = -expf(av.y) * 1.44269504f;
        aL2[q*4+2] = -expf(av.z) * 1.44269504f;
        aL2[q*4+3] = -expf(av.w) * 1.44269504f;
    }
    __syncthreads();
    float h[16] = {};
    float sdt = 0.f;
    const float*  dtp = dt  + (size_t)(b * TL + t0) * DI + d;
    const ushort* up  = u16 + (size_t)(b * TL + t0) * DI + d;
    for (int t = 0; t < TC; ++t) {
        const float dtv = dtp[(size_t)t * DI];
        const float uv  = bf2f(up[(size_t)t * DI]);
        const float du  = dtv * uv;
        sdt += dtv;
        float Bv[16];
        *(float4*)&Bv[0]  = *(const float4*)&bc[t][0];
        *(float4*)&Bv[4]  = *(const float4*)&bc[t][4];
        *(float4*)&Bv[8]  = *(const float4*)&bc[t][8];
        *(float4*)&Bv[12] = *(const float4*)&bc[t][12];
#pragma unroll
        for (int n = 0; n < 16; ++n)
            h[n] = h[n] * exp2f(dtv * aL2[n]) + du * Bv[n];
    }
    float* ho = hA + ((size_t)((b * NCH + c) * DI) + d) * 16;
#pragma unroll
    for (int q = 0; q < 4; ++q)
        *(float4*)(ho + q * 4) = *(float4*)&h[q * 4];
    sdtA[(size_t)(b * NCH + c) * DI + d] = sdt;
}

__global__ __launch_bounds__(256) void scan_partB(
    const float* __restrict__ hA, const float* __restrict__ sdtA,
    const float* __restrict__ A_log, float* __restrict__ Hs)
{
    const int idx = blockIdx.x * 256 + threadIdx.x;   // NB*DI*16
    const int n = idx & 15;
    const int d = (idx >> 4) & (DI - 1);
    const int b = idx >> 15;
    const float aL2 = -expf(A_log[(size_t)d * NST + n]) * 1.44269504f;
    float H = 0.f;
    for (int c = 0; c < NCH; ++c) {
        const size_t base = (size_t)(b * NCH + c) * DI + d;
        Hs[base * 16 + n] = H;
        H = hA[base * 16 + n] + exp2f(aL2 * sdtA[base]) * H;
    }
}

__global__ __launch_bounds__(256) void scan_partC(
    const float* __restrict__ dt, const ushort* __restrict__ u16,
    const float* __restrict__ xdbl, const float* __restrict__ A_log,
    const float* __restrict__ D_skip, const ushort* __restrict__ g16,
    const float* __restrict__ Hs, ushort* __restrict__ y16)
{
    __shared__ float bc[TC][32];
    const int tid = threadIdx.x;
    const int d  = blockIdx.x * 256 + tid;
    const int c  = blockIdx.y;
    const int b  = blockIdx.z;
    const int t0 = c * TC;
    {
        const int r = tid >> 3, cq = tid & 7;
        const float* src = xdbl + (size_t)(b * TL + t0 + r) * XDBL + 64 + cq * 4;
        *(float4*)&bc[r][cq * 4] = *(const float4*)src;
    }
    float aL2[16];
#pragma unroll
    for (int q = 0; q < 4; ++q) {
        const float4 av = *(const float4*)(A_log + (size_t)d * NST + q * 4);
        aL2[q*4+0] = -expf(av.x) * 1.44269504f;
        aL2[q*4+1] = -expf(av.y) * 1.44269504f;
        aL2[q*4+2] = -expf(av.z) * 1.44269504f;
        aL2[q*4+3] = -expf(av.w) * 1.44269504f;
    }
    float h[16];
    const float* hi = Hs + ((size_t)((b * NCH + c) * DI) + d) * 16;
#pragma unroll
    for (int q = 0; q < 4; ++q)
        *(float4*)&h[q * 4] = *(const float4*)(hi + q * 4);
    const float Dv = D_skip[d];
    __syncthreads();
    const float*  dtp = dt  + (size_t)(b * TL + t0) * DI + d;
    const ushort* up  = u16 + (size_t)(b * TL + t0) * DI + d;
    const ushort* gp  = g16 + (size_t)(b * TL + t0) * DI + d;
    ushort*       yp  = y16 + (size_t)(b * TL + t0) * DI + d;
    for (int t = 0; t < TC; ++t) {
        const float dtv = dtp[(size_t)t * DI];
        const float uv  = bf2f(up[(size_t)t * DI]);
        const float du  = dtv * uv;
        float Bv[16], Cv[16];
        *(float4*)&Bv[0]  = *(const float4*)&bc[t][0];
        *(float4*)&Bv[4]  = *(const float4*)&bc[t][4];
        *(float4*)&Bv[8]  = *(const float4*)&bc[t][8];
        *(float4*)&Bv[12] = *(const float4*)&bc[t][12];
        *(float4*)&Cv[0]  = *(const float4*)&bc[t][16];
        *(float4*)&Cv[4]  = *(const float4*)&bc[t][20];
        *(float4*)&Cv[8]  = *(const float4*)&bc[t][24];
        *(float4*)&Cv[12] = *(const float4*)&bc[t][28];
#pragma unroll
        for (int n = 0; n < 16; ++n)
            h[n] = h[n] * exp2f(dtv * aL2[n]) + du * Bv[n];
        float y0 = 0.f, y1 = 0.f, y2 = 0.f, y3 = 0.f;
#pragma unroll
        for (int n = 0; n < 4; ++n) {
            y0 += h[n]      * Cv[n];
            y1 += h[n + 4]  * Cv[n + 4];
            y2 += h[n + 8]  * Cv[n + 8];
            y3 += h[n + 12] * Cv[n + 12];
        }
        const float y = (y0 + y1) + (y2 + y3);
        const float g = bf2f(gp[(size_t)t * DI]);
        yp[(size_t)t * DI] = f2bf((y + uv * Dv) * g);
    }
}

extern "C" void kernel_launch(void* const* d_in, const int* in_sizes, int n_in,
                              void* d_out, int out_size, void* d_ws, size_t ws_size,
                              hipStream_t stream)
{
    const float* x      = (const float*)d_in[0];
    const float* ln_w   = (const float*)d_in[1];
    const float* ln_b   = (const float*)d_in[2];
    const float* in_w   = (const float*)d_in[3];
    const float* cw     = (const float*)d_in[4];
    const float* cb     = (const float*)d_in[5];
    const float* xp_w   = (const float*)d_in[6];
    const float* dtp_w  = (const float*)d_in[7];
    const float* dtp_b  = (const float*)d_in[8];
    const float* A_log  = (const float*)d_in[9];
    const float* D_skip = (const float*)d_in[10];
    const float* out_w  = (const float*)d_in[11];
    float* out = (float*)d_out;

    char* p = (char*)d_ws;
    float*  xz     = (float*)p;  p += (size_t)BT * 4096 * 4;   // 64MB
    float*  dtb    = (float*)p;  p += (size_t)BT * DI * 4;     // 32MB
    float*  xdbl   = (float*)p;  p += (size_t)BT * XDBL * 4;   // 1.5MB
    ushort* xn16   = (ushort*)p; p += (size_t)BT * DM * 2;     // 8MB
    ushort* u16    = (ushort*)p; p += (size_t)BT * DI * 2;     // 16MB
    ushort* g16    = (ushort*)p; p += (size_t)BT * DI * 2;     // 16MB
    ushort* y16    = (ushort*)p; p += (size_t)BT * DI * 2;     // 16MB
    ushort* xdbl16 = (ushort*)p; p += (size_t)BT * XDBL * 2;   // 0.75MB
    ushort* inw16  = (ushort*)p; p += (size_t)2 * 4096 * DM * 2;   // 16.8MB
    ushort* xpw16  = (ushort*)p; p += (size_t)2 * 128 * DI * 2;    // 1MB
    ushort* dtpw16 = (ushort*)p; p += (size_t)2 * DI * DTR * 2;    // 0.5MB
    ushort* outw16 = (ushort*)p; p += (size_t)2 * DM * DI * 2;     // 8.4MB

    // scan scratch + x_proj partials alias the xz region (free after conv)
    float* hA    = xz;                                   // NB*NCH*DI*16 = 16.8MB
    float* Hs    = hA + (size_t)NB * NCH * DI * 16;      // 16.8MB
    float* sdtA  = Hs + (size_t)NB * NCH * DI * 16;      // 1MB
    float* parts = sdtA + (size_t)NB * NCH * DI;         // 4*BT*96 = 6.3MB

    // weight conversions (both layers)
    cvt4<<<(2 * 4096 * DM / 4) / 256, 256, 0, stream>>>(in_w, inw16);
    cvt_xpw_k<<<(2 * 128 * DI / 4) / 256, 256, 0, stream>>>(xp_w, xpw16);
    cvt4<<<(2 * DI * DTR / 4) / 256, 256, 0, stream>>>(dtp_w, dtpw16);
    cvt4<<<(2 * DM * DI / 4) / 256, 256, 0, stream>>>(out_w, outw16);

    for (int L = 0; L < 2; ++L) {
        const float* xin = (L == 0) ? x : out;
        ln_kernel<<<BT, 256, 0, stream>>>(xin, ln_w + L * DM, ln_b + L * DM, xn16);
        // in_proj: (BT,1024)x(4096,1024)^T -> xz f32
        gemm_bf16<0><<<dim3(32, 32, 1), 256, 0, stream>>>(
            xn16, inw16 + (size_t)L * 4096 * DM, xz, nullptr,
            DM, DM, DM, 4096, 4096, 0);
        conv_silu_kernel<<<(BT * (DI / 4)) / 256, 256, 0, stream>>>(
            xz, cw + (size_t)L * DI * 4, cb + (size_t)L * DI, u16, g16);
        // x_proj split-K: (BT,2048)x(96,2048)^T -> 4 partials -> xdbl
        gemm_bf16<4><<<dim3(1, 32, 4), 256, 0, stream>>>(
            u16, xpw16 + (size_t)L * 128 * DI, parts, nullptr,
            DI / 4, DI, DI, XDBL, XDBL, (size_t)BT * XDBL);
        xdbl_reduce<<<(BT * XDBL / 4) / 256, 256, 0, stream>>>(parts, xdbl, xdbl16);
        // dt_proj + softplus: (BT,64)x(2048,64)^T -> dtb f32
        gemm_bf16<2><<<dim3(16, 32, 1), 256, 0, stream>>>(
            xdbl16, dtpw16 + (size_t)L * DI * DTR, dtb, dtp_b + (size_t)L * DI,
            DTR, XDBL, DTR, DI, DI, 0);
        // chunked selective scan
        scan_partA<<<dim3(DI / 256, NCH, NB), 256, 0, stream>>>(
            dtb, u16, xdbl, A_log + (size_t)L * DI * NST, hA, sdtA);
        scan_partB<<<(NB * DI * 16) / 256, 256, 0, stream>>>(
            hA, sdtA, A_log + (size_t)L * DI * NST, Hs);
        scan_partC<<<dim3(DI / 256, NCH, NB), 256, 0, stream>>>(
            dtb, u16, xdbl, A_log + (size_t)L * DI * NST,
            D_skip + (size_t)L * DI, g16, Hs, y16);
        // out_proj + residual: (BT,2048)x(1024,2048)^T + xin -> out
        gemm_bf16<3><<<dim3(8, 32, 1), 256, 0, stream>>>(
            y16, outw16 + (size_t)L * DM * DI, out, xin,
            DI, DI, DI, DM, DM, 0);
    }
}